// Round 13
// baseline (7578.062 us; speedup 1.0000x reference)
//
#include <hip/hip_runtime.h>
#include <hip/hip_bf16.h>

#define S_LEN 2048
#define NB    32
#define NK    512     // IN_DIM == HID == 512
#define NH    512
#define N4H   2048
#define NWG   32
#define JPW   16      // hidden columns per WG (2 col-tiles of 32x32)

typedef __attribute__((ext_vector_type(8)))  short    short8;
typedef __attribute__((ext_vector_type(4)))  float    floatx4;
typedef __attribute__((ext_vector_type(2)))  float    floatx2;
typedef __attribute__((ext_vector_type(16))) float    floatx16;
typedef __attribute__((ext_vector_type(4)))  unsigned uintx4;
typedef __attribute__((ext_vector_type(2)))  unsigned uintx2;

__device__ __forceinline__ unsigned f2bf(float f) {
  union { float f; unsigned u; } v; v.f = f;
  unsigned r = v.u + 0x7fffu + ((v.u >> 16) & 1u);
  return r >> 16;
}
__device__ __forceinline__ float sigm(float x) { return 1.f / (1.f + __expf(-x)); }
__device__ __forceinline__ float ftanh(float x) {
  float e = __expf(2.f * x);
  return 1.f - 2.f / (e + 1.f);
}

// 16 x 16B poll loads of this lane's h slice (tagged u32), no wait.
#define HLOAD16F                                                        \
  asm volatile(                                                         \
    "global_load_dwordx4 %0,  %[p0], off sc1\n\t"                       \
    "global_load_dwordx4 %1,  %[p0], off offset:16 sc1\n\t"             \
    "global_load_dwordx4 %2,  %[p0], off offset:1024 sc1\n\t"           \
    "global_load_dwordx4 %3,  %[p0], off offset:1040 sc1\n\t"           \
    "global_load_dwordx4 %4,  %[p0], off offset:2048 sc1\n\t"           \
    "global_load_dwordx4 %5,  %[p0], off offset:2064 sc1\n\t"           \
    "global_load_dwordx4 %6,  %[p0], off offset:3072 sc1\n\t"           \
    "global_load_dwordx4 %7,  %[p0], off offset:3088 sc1\n\t"           \
    "global_load_dwordx4 %8,  %[p1], off sc1\n\t"                       \
    "global_load_dwordx4 %9,  %[p1], off offset:16 sc1\n\t"             \
    "global_load_dwordx4 %10, %[p1], off offset:1024 sc1\n\t"           \
    "global_load_dwordx4 %11, %[p1], off offset:1040 sc1\n\t"           \
    "global_load_dwordx4 %12, %[p1], off offset:2048 sc1\n\t"           \
    "global_load_dwordx4 %13, %[p1], off offset:2064 sc1\n\t"           \
    "global_load_dwordx4 %14, %[p1], off offset:3072 sc1\n\t"           \
    "global_load_dwordx4 %15, %[p1], off offset:3088 sc1"               \
    : "=&v"(h0),  "=&v"(h1),  "=&v"(h2),  "=&v"(h3),                    \
      "=&v"(h4),  "=&v"(h5),  "=&v"(h6),  "=&v"(h7),                    \
      "=&v"(h8),  "=&v"(h9),  "=&v"(h10), "=&v"(h11),                   \
      "=&v"(h12), "=&v"(h13), "=&v"(h14), "=&v"(h15)                    \
    : [p0] "v"(ap0), [p1] "v"(ap1) : "memory")

// EVERY dword is (value16<<16)|tag16; 4B writes are atomic, so checking all
// four dwords of each 16B unit detects tearing at any store/load granularity.
#define CHK1(x) ((x[0]^e16) | (x[1]^e16) | (x[2]^e16) | (x[3]^e16))
#define CHKALL do { bad = (CHK1(h0)  | CHK1(h1)  | CHK1(h2)  | CHK1(h3)        \
                         | CHK1(h4)  | CHK1(h5)  | CHK1(h6)  | CHK1(h7)        \
                         | CHK1(h8)  | CHK1(h9)  | CHK1(h10) | CHK1(h11)       \
                         | CHK1(h12) | CHK1(h13) | CHK1(h14) | CHK1(h15))      \
                         & 0xffffu; } while (0)

// LDS-only barrier: no vmcnt drain (unlike __syncthreads)
#define WG_BARRIER_LDS do {                                                    \
    __builtin_amdgcn_sched_barrier(0);                                         \
    asm volatile("s_waitcnt lgkmcnt(0)\n\ts_barrier" ::: "memory");            \
    __builtin_amdgcn_sched_barrier(0); } while (0)

__global__ __launch_bounds__(256, 1) void plstm_persist(
    const float* __restrict__ X,  const float* __restrict__ Wx, const float* __restrict__ bx,
    const float* __restrict__ Wh, const float* __restrict__ bh, const float* __restrict__ zc,
    float* __restrict__ out, char* __restrict__ hbuf)   // 2 x 64KB tagged-bf16 h
{
  const int tid  = threadIdx.x;
  const int g    = blockIdx.x;
  const int wv   = tid >> 6, lane = tid & 63;
  const int colN = lane & 31, kgrp = lane >> 5;
  const int arow = colN;
  const int jbase = g * JPW;

  // B-fragments (weights) in registers: 2 col-tiles x this wave's K-quarter
  short8 wxr[2][8], whr[2][8];
  #pragma unroll
  for (int ct = 0; ct < 2; ++ct) {
    const int nl = ct * 32 + colN;
    const int nglob = (nl >> 4) * NH + jbase + (nl & 15);
    #pragma unroll
    for (int it = 0; it < 8; ++it) {
      const int k0 = wv * 128 + it * 16 + kgrp * 8;
      short8 a, b;
      #pragma unroll
      for (int e = 0; e < 8; ++e) {
        a[e] = (short)f2bf(Wx[(size_t)(k0 + e) * N4H + nglob]);
        b[e] = (short)f2bf(Wh[(size_t)(k0 + e) * N4H + nglob]);
      }
      wxr[ct][it] = a; whr[ct][it] = b;
    }
  }

  const int m_own = tid >> 3;
  const int jp    = (tid & 7) * 2;
  float bsA[4], bsB[4];
  #pragma unroll
  for (int q = 0; q < 4; ++q) {
    bsA[q] = bx[q*NH + jbase + jp]     + bh[q*NH + jbase + jp];
    bsB[q] = bx[q*NH + jbase + jp + 1] + bh[q*NH + jbase + jp + 1];
  }
  const float zcA = zc[jbase + jp], zcB = zc[jbase + jp + 1];
  float csA = 0.f, csB = 0.f;

  __shared__ float lds_acc[4][32][72];

  // direct-publish slot: this thread's 2 values inside granule layout
  char* const pub = hbuf
      + (size_t)((((g >> 3) * 2 + ((jp >> 3) & 1)) * 8 + (g & 7)) * 1024
                 + m_own * 32 + (jp & 7) * 4);

  // prologue: convert X[0], issue X[1] prefetch
  short8 xf[8];
  floatx4 xnew[16];
  {
    const floatx4* p0 = (const floatx4*)(X + arow * NK);
    #pragma unroll
    for (int it = 0; it < 8; ++it) {
      const int k0 = wv * 128 + it * 16 + kgrp * 8;
      floatx4 x0 = p0[k0 >> 2], x1 = p0[(k0 >> 2) + 1];
      short8 a;
      #pragma unroll
      for (int e = 0; e < 4; ++e) { a[e] = (short)f2bf(x0[e]); a[4+e] = (short)f2bf(x1[e]); }
      xf[it] = a;
    }
    const floatx4* p1 = (const floatx4*)(X + (size_t)NB * NK + arow * NK);
    #pragma unroll
    for (int it = 0; it < 8; ++it) {
      const int k0 = wv * 128 + it * 16 + kgrp * 8;
      xnew[2 * it]     = p1[k0 >> 2];
      xnew[2 * it + 1] = p1[(k0 >> 2) + 1];
    }
  }

  for (int t = 0; t < S_LEN; ++t) {
    uintx4 h0, h1, h2, h3, h4, h5, h6, h7, h8, h9, h10, h11, h12, h13, h14, h15;
    const char* ap0 = hbuf + (size_t)((t - 1) & 1) * 65536
                    + (wv * 2 + kgrp) * 8192 + arow * 32;
    const char* ap1 = ap0 + 4096;

    if (t > 0) {
      HLOAD16F;                      // h poll loads first
      // convert X[t] (compiler waits the exact vmcnt for xnew)
      #pragma unroll
      for (int it = 0; it < 8; ++it) {
        short8 a;
        #pragma unroll
        for (int e = 0; e < 4; ++e) {
          a[e]   = (short)f2bf(xnew[2*it][e]);
          a[4+e] = (short)f2bf(xnew[2*it+1][e]);
        }
        xf[it] = a;
      }
    }

    floatx16 acc0, acc1;
    #pragma unroll
    for (int r = 0; r < 16; ++r) { acc0[r] = 0.f; acc1[r] = 0.f; }

    // input-projection MFMAs (cover h-load latency)
    #pragma unroll
    for (int it = 0; it < 8; ++it) {
      acc0 = __builtin_amdgcn_mfma_f32_32x32x16_bf16(xf[it], wxr[0][it], acc0, 0,0,0);
      acc1 = __builtin_amdgcn_mfma_f32_32x32x16_bf16(xf[it], wxr[1][it], acc1, 0,0,0);
    }

    if (t > 0) {
      const unsigned e16 = (unsigned)t & 0xffffu;   // tag = publisher step + 1
      unsigned bad;
      asm volatile("s_waitcnt vmcnt(0)" ::: "memory");
      __builtin_amdgcn_sched_barrier(0);
      CHKALL;
      if (__any((int)(bad != 0u))) {
        // one immediate fast retry (data was "almost there")
        HLOAD16F;
        asm volatile("s_waitcnt vmcnt(0)" ::: "memory");
        __builtin_amdgcn_sched_barrier(0);
        CHKALL;
        // then back off ~128cy between rounds: decongest the LLC window
        while (__any((int)(bad != 0u))) {
          __builtin_amdgcn_s_sleep(2);
          HLOAD16F;
          asm volatile("s_waitcnt vmcnt(0)" ::: "memory");
          __builtin_amdgcn_sched_barrier(0);
          CHKALL;
        }
      }
      // reassemble bf16 fragments: d = (lo>>16) | (hi<<16), no float math
      uintx4 hq[16] = { h0, h1, h2, h3, h4, h5, h6, h7,
                        h8, h9, h10, h11, h12, h13, h14, h15 };
      #pragma unroll
      for (int it = 0; it < 8; ++it) {
        const uintx4 lo = hq[2 * it], hi = hq[2 * it + 1];
        union { uintx4 u; short8 s; } cv;
        cv.u[0] = (lo[0] >> 16) | (lo[1] & 0xffff0000u);
        cv.u[1] = (lo[2] >> 16) | (lo[3] & 0xffff0000u);
        cv.u[2] = (hi[0] >> 16) | (hi[1] & 0xffff0000u);
        cv.u[3] = (hi[2] >> 16) | (hi[3] & 0xffff0000u);
        acc0 = __builtin_amdgcn_mfma_f32_32x32x16_bf16(cv.s, whr[0][it], acc0, 0,0,0);
        acc1 = __builtin_amdgcn_mfma_f32_32x32x16_bf16(cv.s, whr[1][it], acc1, 0,0,0);
      }
      // X[t+1] prefetch: issued post-poll, lands under reduce+gates+next top
      if (t + 1 < S_LEN) {
        const floatx4* p = (const floatx4*)(X + (size_t)(t + 1) * NB * NK + arow * NK);
        #pragma unroll
        for (int it = 0; it < 8; ++it) {
          const int k0 = wv * 128 + it * 16 + kgrp * 8;
          xnew[2 * it]     = p[k0 >> 2];
          xnew[2 * it + 1] = p[(k0 >> 2) + 1];
        }
      }
    }

    // cross-wave K-reduction (LDS-only barrier: no vmcnt drain)
    #pragma unroll
    for (int r = 0; r < 16; ++r) {
      const int row = (r & 3) + 8 * (r >> 2) + 4 * kgrp;   // verified 32x32 C/D layout
      lds_acc[wv][row][colN]      = acc0[r];
      lds_acc[wv][row][36 + colN] = acc1[r];
    }
    WG_BARRIER_LDS;

    float preA[4], preB[4];
    #pragma unroll
    for (int q = 0; q < 4; ++q) {
      const int cc = (q >> 1) * 36 + (q & 1) * 16 + jp;
      preA[q] = lds_acc[0][m_own][cc]   + lds_acc[1][m_own][cc]
              + lds_acc[2][m_own][cc]   + lds_acc[3][m_own][cc]   + bsA[q];
      preB[q] = lds_acc[0][m_own][cc+1] + lds_acc[1][m_own][cc+1]
              + lds_acc[2][m_own][cc+1] + lds_acc[3][m_own][cc+1] + bsB[q];
    }
    const float iA = sigm(preA[0]), oA = sigm(preA[1]), fA = sigm(preA[3]);
    const float zA = ftanh(preA[2] + zcA * csA);           // peephole on block input
    csA = iA * zA + fA * csA;
    const float hA = oA * ftanh(csA);
    const float iB = sigm(preB[0]), oB = sigm(preB[1]), fB = sigm(preB[3]);
    const float zB = ftanh(preB[2] + zcB * csB);
    csB = iB * zB + fB * csB;
    const float hB = oB * ftanh(csB);

    // publish FIRST (critical), tagged u32 pair, no ack wait
    if (t + 1 < S_LEN) {
      const unsigned tg = (unsigned)(t + 1) & 0xffffu;
      uintx2 u;
      u[0] = (f2bf(hA) << 16) | tg;
      u[1] = (f2bf(hB) << 16) | tg;
      char* sp = pub + (size_t)(t & 1) * 65536;
      asm volatile("global_store_dwordx2 %0, %1, off sc1"
                   :: "v"(sp), "v"(u) : "memory");
    }

    // output sinks (off critical path)
    floatx2 hv2; hv2[0] = hA; hv2[1] = hB;
    *(floatx2*)&out[((size_t)t * NB + m_own) * NH + jbase + jp] = hv2;
    if (t == S_LEN - 1) {
      *(floatx2*)&out[(size_t)S_LEN * NB * NH + (size_t)m_own * NH + jbase + jp] = hv2;
      floatx2 cv2; cv2[0] = csA; cv2[1] = csB;
      *(floatx2*)&out[(size_t)S_LEN * NB * NH + (size_t)NB * NH
                      + (size_t)m_own * NH + jbase + jp] = cv2;
    }

    WG_BARRIER_LDS;   // WAR on lds_acc (LDS-only; no vmcnt drain)
  }
}

extern "C" void kernel_launch(void* const* d_in, const int* in_sizes, int n_in,
                              void* d_out, int out_size, void* d_ws, size_t ws_size,
                              hipStream_t stream) {
  const float* X  = (const float*)d_in[0];
  const float* Wx = (const float*)d_in[1];
  const float* bx = (const float*)d_in[2];
  const float* Wh = (const float*)d_in[3];
  const float* bh = (const float*)d_in[4];
  const float* zc = (const float*)d_in[5];
  float* out = (float*)d_out;
  char* hbuf = (char*)d_ws;   // 2 x 64KB tagged h; every dword self-validates
                              // (0xAAAA poison never matches a tag), no init needed

  hipLaunchKernelGGL(plstm_persist, dim3(NWG), dim3(256), 0, stream,
                     X, Wx, bx, Wh, bh, zc, out, hbuf);
}